// Round 7
// baseline (975.373 us; speedup 1.0000x reference)
//
#include <hip/hip_runtime.h>

#define DD 64
constexpr int N_P   = 100000;
constexpr int N_G   = 40000;
constexpr int NE    = 1600000;
constexpr int E_LBL = 500000;
constexpr int F_GO  = 1000;
constexpr int KSTEPS = 32;     // K padded to 1024 = 32 steps of 32

// bucketed counting-sort parameters (big buckets, block-aggregated atomics)
constexpr int SHIFT_G = 8;                         // 256 rows per bucket
constexpr int NB_G    = (N_G + 255) >> 8;          // 157
constexpr int SHIFT_P = 9;                         // 512 rows per bucket
constexpr int NB_P    = (N_P + 511) >> 9;          // 196
constexpr int NB_MAX  = 256;
constexpr int W_MAX   = 512;
constexpr int CHUNK   = 8192;                      // edges per bin_fill block

typedef __attribute__((ext_vector_type(8))) short bf16x8;
typedef __attribute__((ext_vector_type(4))) float f32x4;
typedef __attribute__((ext_vector_type(4))) short s16x4;

// ---- fp32 -> bf16 hi/lo split (RNE) ----
__device__ __forceinline__ unsigned short f2bf_rne(float x) {
    unsigned u = __float_as_uint(x);
    u += 0x7fff + ((u >> 16) & 1);
    return (unsigned short)(u >> 16);
}
__device__ __forceinline__ float bf2f(unsigned short h) {
    return __uint_as_float((unsigned)h << 16);
}
struct BfPair { short h; short l; };
__device__ __forceinline__ BfPair split_bf(float x) {
    BfPair p;
    unsigned short hh = f2bf_rne(x);
    unsigned short ll = f2bf_rne(x - bf2f(hh));
    p.h = (short)hh; p.l = (short)ll;
    return p;
}

// ---------------- gather rows: out[i] = emb[nid[i]] ----------------
__global__ void gather_rows(const float* __restrict__ emb, const int* __restrict__ nid,
                            float* __restrict__ out, int n) {
    int t = blockIdx.x * blockDim.x + threadIdx.x;
    int total = n * (DD / 4);
    if (t >= total) return;
    int row = t / (DD / 4);
    int c4  = t % (DD / 4);
    int srow = nid[row];
    reinterpret_cast<float4*>(out)[(size_t)row * (DD / 4) + c4] =
        reinterpret_cast<const float4*>(emb)[(size_t)srow * (DD / 4) + c4];
}

// ---------------- pack lin_W into MFMA B-fragment order, hi/lo bf16 ----------
__global__ void pack_B(const float* __restrict__ lin_W,
                       short* __restrict__ BH, short* __restrict__ BL) {
    int t = blockIdx.x * blockDim.x + threadIdx.x;
    if (t >= KSTEPS * 64 * 4) return;
    int s = t >> 8, n = (t >> 2) & 63, q = t & 3;
    int base = t * 8;
#pragma unroll
    for (int j = 0; j < 8; ++j) {
        int k = s * 32 + q * 8 + j;
        float v = (k < F_GO) ? lin_W[(size_t)k * 64 + n] : 0.f;
        BfPair p = split_bf(v);
        BH[base + j] = p.h;
        BL[base + j] = p.l;
    }
}

// ---------------- xg = go_x @ lin_W (+ lin_b + go_emb via reduce) ----------------
// K split across BLOCKS 2 ways (R5-proven): blockIdx.x&1 -> k-half [0,512)/[512,1024).
// NEW: explicit next-step prefetch of the two HBM float4 loads, so loads pipeline
// across iterations instead of serializing at VGPR=32 (R6 post-mortem).
__global__ __launch_bounds__(256) void lin_go_part(const float* __restrict__ go_x,
        const short* __restrict__ BH, const short* __restrict__ BL,
        float* __restrict__ part0, float* __restrict__ part1) {
    int tid = threadIdx.x;
    int wave = tid >> 6, lane = tid & 63;
    int ml = lane & 15, q = lane >> 4;
    int half = blockIdx.x & 1;
    int row0 = (blockIdx.x >> 1) * 64 + wave * 16;   // 625 * 64 = 40000 exactly
    float* outp = half ? part1 : part0;
    const float* arow = go_x + (size_t)(row0 + ml) * F_GO;
    f32x4 acc[4] = {};
    int s0 = half * 16;
    int send = s0 + 16;
    // prologue: issue step s0's loads
    int kb0 = s0 * 32 + q * 8;
    int kc0 = kb0 > 992 ? 992 : kb0;
    float4 va = *reinterpret_cast<const float4*>(arow + kc0);
    float4 vb = *reinterpret_cast<const float4*>(arow + kc0 + 4);
    for (int s = s0; s < send; ++s) {
        // prefetch step s+1 (redundant re-load of s on last iter; L2-hit, keeps nva defined)
        int sn = (s + 1 < send) ? s + 1 : s;
        int nkb = sn * 32 + q * 8;
        int nkc = nkb > 992 ? 992 : nkb;
        float4 nva = *reinterpret_cast<const float4*>(arow + nkc);
        float4 nvb = *reinterpret_cast<const float4*>(arow + nkc + 4);
        bf16x8 ah, al;
        {
            BfPair p0 = split_bf(va.x), p1 = split_bf(va.y),
                   p2 = split_bf(va.z), p3 = split_bf(va.w);
            BfPair p4 = split_bf(vb.x), p5 = split_bf(vb.y),
                   p6 = split_bf(vb.z), p7 = split_bf(vb.w);
            ah[0]=p0.h; ah[1]=p1.h; ah[2]=p2.h; ah[3]=p3.h;
            ah[4]=p4.h; ah[5]=p5.h; ah[6]=p6.h; ah[7]=p7.h;
            al[0]=p0.l; al[1]=p1.l; al[2]=p2.l; al[3]=p3.l;
            al[4]=p4.l; al[5]=p5.l; al[6]=p6.l; al[7]=p7.l;
        }
#pragma unroll
        for (int nt = 0; nt < 4; ++nt) {
            int off = ((s * 64 + nt * 16 + ml) * 4 + q) * 8;
            bf16x8 bh = *reinterpret_cast<const bf16x8*>(BH + off);
            bf16x8 bl = *reinterpret_cast<const bf16x8*>(BL + off);
            acc[nt] = __builtin_amdgcn_mfma_f32_16x16x32_bf16(ah, bh, acc[nt], 0, 0, 0);
            acc[nt] = __builtin_amdgcn_mfma_f32_16x16x32_bf16(al, bh, acc[nt], 0, 0, 0);
            acc[nt] = __builtin_amdgcn_mfma_f32_16x16x32_bf16(ah, bl, acc[nt], 0, 0, 0);
        }
        va = nva; vb = nvb;
    }
    // epilogue: C/D layout col=lane&15, row=q*4+reg (round-2 mapping, raw partial)
#pragma unroll
    for (int reg = 0; reg < 4; ++reg) {
        int row = row0 + q * 4 + reg;
#pragma unroll
        for (int nt = 0; nt < 4; ++nt) {
            int col = nt * 16 + ml;
            outp[(size_t)row * 64 + col] = acc[nt][reg];
        }
    }
}

// g0 = g0 + g1 + lin_b + go_emb[go_nid]
__global__ void lin_go_reduce(float* __restrict__ g0, const float* __restrict__ g1,
        const float* __restrict__ lin_b, const float* __restrict__ go_emb,
        const int* __restrict__ go_nid) {
    int t = blockIdx.x * blockDim.x + threadIdx.x;
    if (t >= N_G * 16) return;
    int row = t >> 4;
    int c4  = (t & 15) * 4;
    int nid = go_nid[row];
    float4 a  = *reinterpret_cast<const float4*>(g0 + (size_t)row * 64 + c4);
    float4 b  = *reinterpret_cast<const float4*>(g1 + (size_t)row * 64 + c4);
    float4 bb = *reinterpret_cast<const float4*>(lin_b + c4);
    float4 ee = *reinterpret_cast<const float4*>(go_emb + (size_t)nid * 64 + c4);
    float4 r;
    r.x = a.x + b.x + bb.x + ee.x;
    r.y = a.y + b.y + bb.y + ee.y;
    r.z = a.z + b.z + bb.z + ee.z;
    r.w = a.w + b.w + bb.w + ee.w;
    *reinterpret_cast<float4*>(g0 + (size_t)row * 64 + c4) = r;
}

// ================= bucketed CSR build (block-aggregated atomics) =================
// Phase 1: per-block LDS histogram of dst>>shift, one flush atomic per bucket/block
__global__ __launch_bounds__(256) void bin_count(const int* __restrict__ dst,
        int* __restrict__ cnt, int nE, int shift, int nb) {
    __shared__ int h[NB_MAX];
    for (int i = threadIdx.x; i < nb; i += 256) h[i] = 0;
    __syncthreads();
    for (int e = blockIdx.x * blockDim.x + threadIdx.x; e < nE; e += gridDim.x * blockDim.x)
        atomicAdd(&h[dst[e] >> shift], 1);
    __syncthreads();
    for (int i = threadIdx.x; i < nb; i += 256)
        if (h[i]) atomicAdd(&cnt[i], h[i]);
}

// Phase 2: exclusive scan of bucket counts (single block; nb <= 256)
__global__ __launch_bounds__(256) void scan_buckets(const int* __restrict__ cnt,
        int* __restrict__ base, int* __restrict__ cursor, int nb, int total) {
    __shared__ int sh[NB_MAX];
    int v = (threadIdx.x < nb) ? cnt[threadIdx.x] : 0;
    sh[threadIdx.x] = v;
    __syncthreads();
    for (int off = 1; off < NB_MAX; off <<= 1) {
        int t = (threadIdx.x >= off) ? sh[threadIdx.x - off] : 0;
        __syncthreads();
        sh[threadIdx.x] += t;
        __syncthreads();
    }
    if (threadIdx.x < nb) {
        int ex = sh[threadIdx.x] - v;
        base[threadIdx.x] = ex;
        cursor[threadIdx.x] = ex;
    }
    if (threadIdx.x == 0) base[nb] = total;
}

// Phase 3: per-block LDS histogram -> ONE global atomic reservation per bucket,
// then scatter pairs into the block's private contiguous segments.
__global__ __launch_bounds__(256) void bin_fill(const int* __restrict__ src,
        const int* __restrict__ dst, int* __restrict__ cursor,
        int2* __restrict__ binned, int nE, int shift, int nb) {
    __shared__ int hist[NB_MAX];
    __shared__ int base[NB_MAX];
    int e0 = blockIdx.x * CHUNK;
    int e1 = e0 + CHUNK; if (e1 > nE) e1 = nE;
    for (int i = threadIdx.x; i < nb; i += 256) hist[i] = 0;
    __syncthreads();
    for (int e = e0 + threadIdx.x; e < e1; e += 256)
        atomicAdd(&hist[dst[e] >> shift], 1);
    __syncthreads();
    // one reservation atomic per (block, bucket); same thread owns index i in both loops
    for (int i = threadIdx.x; i < nb; i += 256) {
        int c = hist[i];
        base[i] = c ? atomicAdd(&cursor[i], c) : 0;
        hist[i] = 0;                       // becomes the block-local running cursor
    }
    __syncthreads();
    for (int e = e0 + threadIdx.x; e < e1; e += 256) {
        int d = dst[e];
        int b = d >> shift;
        int slot = base[b] + atomicAdd(&hist[b], 1);
        binned[slot] = make_int2(src[e], d);
    }
}

// Phase 4: one workgroup per bucket. LDS histogram over the bucket's dst range,
// parallel scan -> rowptr, then scatter csr_src into the bucket's contiguous
// (L2-resident) output window.
__global__ __launch_bounds__(256) void bucket_to_csr(const int2* __restrict__ binned,
        const int* __restrict__ bbase, int* __restrict__ rowptr, int* __restrict__ csr_src,
        int n, int shift, int nE) {
    int b = blockIdx.x;
    int W = 1 << shift;                    // 256 or 512
    int mask = W - 1;
    __shared__ int hist[W_MAX];
    __shared__ int curs[W_MAX];
    int s = bbase[b], e = bbase[b + 1];
    for (int i = threadIdx.x; i < W; i += 256) hist[i] = 0;
    __syncthreads();
    for (int i = s + threadIdx.x; i < e; i += 256)
        atomicAdd(&hist[binned[i].y & mask], 1);
    __syncthreads();
    // inclusive Hillis-Steele scan of hist into curs (W <= 512, 256 threads)
    for (int i = threadIdx.x; i < W; i += 256) curs[i] = hist[i];
    __syncthreads();
    for (int off = 1; off < W; off <<= 1) {
        int i0 = threadIdx.x, i1 = threadIdx.x + 256;
        int t0 = (i0 >= off && i0 < W) ? curs[i0 - off] : 0;
        int t1 = (i1 >= off && i1 < W) ? curs[i1 - off] : 0;
        __syncthreads();
        if (i0 < W) curs[i0] += t0;
        if (i1 < W) curs[i1] += t1;
        __syncthreads();
    }
    int row0 = b << shift;
    for (int j = threadIdx.x; j < W; j += 256) {
        int start = s + curs[j] - hist[j]; // exclusive prefix + bucket base
        hist[j] = start;                   // becomes the per-row running cursor
        int r = row0 + j;
        if (r < n) rowptr[r] = start;
    }
    if (b == 0 && threadIdx.x == 0) rowptr[n] = nE;
    __syncthreads();
    for (int i = s + threadIdx.x; i < e; i += 256) {
        int2 ed = binned[i];
        int slot = atomicAdd(&hist[ed.y & mask], 1);
        csr_src[slot] = ed.x;
    }
}

// ---------------- aggregation: out[d] = mean over CSR edges of x[src] ----------
// 4 rows/block, 1 wave/row; 4 lane-groups of 16 each own residue class i%4;
// 4 gathers in flight per group to hide L3 latency.
__global__ void aggregate_csr(const float* __restrict__ x, const int* __restrict__ rowptr,
                              const int* __restrict__ csr_src, float* __restrict__ out, int n) {
    int row = blockIdx.x * 4 + (threadIdx.x >> 6);
    if (row >= n) return;
    int lane = threadIdx.x & 63;
    int qg   = lane >> 4;
    int l16  = lane & 15;
    int s = rowptr[row], e = rowptr[row + 1];
    const float4* x4 = reinterpret_cast<const float4*>(x);
    float4 a0 = make_float4(0.f, 0.f, 0.f, 0.f);
    float4 a1 = make_float4(0.f, 0.f, 0.f, 0.f);
    float4 a2 = make_float4(0.f, 0.f, 0.f, 0.f);
    float4 a3 = make_float4(0.f, 0.f, 0.f, 0.f);
    int i = s + qg;
    for (; i + 12 < e; i += 16) {
        int s0 = csr_src[i];
        int s1 = csr_src[i + 4];
        int s2 = csr_src[i + 8];
        int s3 = csr_src[i + 12];
        float4 v0 = x4[(size_t)s0 * 16 + l16];
        float4 v1 = x4[(size_t)s1 * 16 + l16];
        float4 v2 = x4[(size_t)s2 * 16 + l16];
        float4 v3 = x4[(size_t)s3 * 16 + l16];
        a0.x += v0.x; a0.y += v0.y; a0.z += v0.z; a0.w += v0.w;
        a1.x += v1.x; a1.y += v1.y; a1.z += v1.z; a1.w += v1.w;
        a2.x += v2.x; a2.y += v2.y; a2.z += v2.z; a2.w += v2.w;
        a3.x += v3.x; a3.y += v3.y; a3.z += v3.z; a3.w += v3.w;
    }
    for (; i < e; i += 4) {
        int s0 = csr_src[i];
        float4 v0 = x4[(size_t)s0 * 16 + l16];
        a0.x += v0.x; a0.y += v0.y; a0.z += v0.z; a0.w += v0.w;
    }
    a0.x += a1.x; a0.y += a1.y; a0.z += a1.z; a0.w += a1.w;
    a2.x += a3.x; a2.y += a3.y; a2.z += a3.z; a2.w += a3.w;
    a0.x += a2.x; a0.y += a2.y; a0.z += a2.z; a0.w += a2.w;
    a0.x += __shfl_xor(a0.x, 16); a0.y += __shfl_xor(a0.y, 16);
    a0.z += __shfl_xor(a0.z, 16); a0.w += __shfl_xor(a0.w, 16);
    a0.x += __shfl_xor(a0.x, 32); a0.y += __shfl_xor(a0.y, 32);
    a0.z += __shfl_xor(a0.z, 32); a0.w += __shfl_xor(a0.w, 32);
    if (qg == 0) {
        float inv = (e > s) ? 1.0f / (float)(e - s) : 0.0f;
        float4 r = make_float4(a0.x * inv, a0.y * inv, a0.z * inv, a0.w * inv);
        reinterpret_cast<float4*>(out)[(size_t)row * 16 + l16] = r;
    }
}

// ---------------- node update: out = agg@Wl + bias + x@Wr (bf16x3 MFMA) ----
constexpr int LDA_UN = 72;
__global__ __launch_bounds__(256) void update_nodes_mfma(
        const float* agg, const float* __restrict__ x,
        const float* __restrict__ Wl, const float* __restrict__ bias,
        const float* __restrict__ Wr, float* out, int n, int relu) {
    __shared__ short Ah[64][LDA_UN], Al[64][LDA_UN];
    __shared__ short Bh[64][LDA_UN], Bl[64][LDA_UN];
    int tid = threadIdx.x;
    int wave = tid >> 6, lane = tid & 63;
    int ml = lane & 15, q = lane >> 4;
    int row0 = blockIdx.x * 64;
    f32x4 acc[4] = {};
    for (int half = 0; half < 2; ++half) {
        const float* Xsrc = half ? x : agg;
        const float* Wsrc = half ? Wr : Wl;
        {
            int k4 = tid & 15;
            for (int r = tid >> 4; r < 64; r += 16) {
                int grow = row0 + r; if (grow >= n) grow = n - 1;
                float4 v = *reinterpret_cast<const float4*>(&Xsrc[(size_t)grow * 64 + k4 * 4]);
                s16x4 h, l;
                BfPair p0 = split_bf(v.x), p1 = split_bf(v.y),
                       p2 = split_bf(v.z), p3 = split_bf(v.w);
                h[0] = p0.h; h[1] = p1.h; h[2] = p2.h; h[3] = p3.h;
                l[0] = p0.l; l[1] = p1.l; l[2] = p2.l; l[3] = p3.l;
                *reinterpret_cast<s16x4*>(&Ah[r][k4 * 4]) = h;
                *reinterpret_cast<s16x4*>(&Al[r][k4 * 4]) = l;
            }
        }
        {
            int nn = tid & 63;
            for (int kr = tid >> 6; kr < 64; kr += 4) {
                float v = Wsrc[(size_t)kr * 64 + nn];
                BfPair p = split_bf(v);
                Bh[nn][kr] = p.h; Bl[nn][kr] = p.l;
            }
        }
        __syncthreads();
#pragma unroll
        for (int kc = 0; kc < 64; kc += 32) {
            int kb = kc + q * 8;
            int m = wave * 16 + ml;
            bf16x8 ah = *reinterpret_cast<const bf16x8*>(&Ah[m][kb]);
            bf16x8 al = *reinterpret_cast<const bf16x8*>(&Al[m][kb]);
#pragma unroll
            for (int nt = 0; nt < 4; ++nt) {
                int nn = nt * 16 + ml;
                bf16x8 bh = *reinterpret_cast<const bf16x8*>(&Bh[nn][kb]);
                bf16x8 bl = *reinterpret_cast<const bf16x8*>(&Bl[nn][kb]);
                acc[nt] = __builtin_amdgcn_mfma_f32_16x16x32_bf16(ah, bh, acc[nt], 0, 0, 0);
                acc[nt] = __builtin_amdgcn_mfma_f32_16x16x32_bf16(al, bh, acc[nt], 0, 0, 0);
                acc[nt] = __builtin_amdgcn_mfma_f32_16x16x32_bf16(ah, bl, acc[nt], 0, 0, 0);
            }
        }
        __syncthreads();
    }
#pragma unroll
    for (int reg = 0; reg < 4; ++reg) {
        int row = row0 + wave * 16 + q * 4 + reg;
        if (row >= n) continue;
#pragma unroll
        for (int nt = 0; nt < 4; ++nt) {
            int col = nt * 16 + ml;
            float v = acc[nt][reg] + bias[col];
            if (relu) v = fmaxf(v, 0.0f);
            out[(size_t)row * 64 + col] = v;
        }
    }
}

// ---------------- classifier ----------------
__global__ void classify(const float* __restrict__ xp, const float* __restrict__ xg,
                         const int* __restrict__ ls, const int* __restrict__ ld,
                         float* __restrict__ out, int nE) {
    int t = blockIdx.x * blockDim.x + threadIdx.x;
    int e = t >> 4;
    int l16 = t & 15;
    if (e >= nE) return;
    int s = ls[e], d = ld[e];
    float4 a = reinterpret_cast<const float4*>(xp)[(size_t)s * 16 + l16];
    float4 b = reinterpret_cast<const float4*>(xg)[(size_t)d * 16 + l16];
    float v = a.x * b.x + a.y * b.y + a.z * b.z + a.w * b.w;
    v += __shfl_xor(v, 8);
    v += __shfl_xor(v, 4);
    v += __shfl_xor(v, 2);
    v += __shfl_xor(v, 1);
    if (l16 == 0) out[e] = v;
}

extern "C" void kernel_launch(void* const* d_in, const int* in_sizes, int n_in,
                              void* d_out, int out_size, void* d_ws, size_t ws_size,
                              hipStream_t stream) {
    const float* go_x        = (const float*)d_in[0];
    const float* protein_emb = (const float*)d_in[1];
    const float* go_emb      = (const float*)d_in[2];
    const float* lin_W       = (const float*)d_in[3];
    const float* lin_b       = (const float*)d_in[4];
    const float* Wl          = (const float*)d_in[5];
    const float* bl          = (const float*)d_in[6];
    const float* Wr          = (const float*)d_in[7];
    const int* protein_nid   = (const int*)d_in[8];
    const int* go_nid        = (const int*)d_in[9];
    const int* src_pg        = (const int*)d_in[10];
    const int* dst_pg        = (const int*)d_in[11];
    const int* src_gp        = (const int*)d_in[12];
    const int* dst_gp        = (const int*)d_in[13];
    const int* label_src     = (const int*)d_in[14];
    const int* label_dst     = (const int*)d_in[15];
    float* out = (float*)d_out;

    float* ws = (float*)d_ws;
    float* p0 = ws;
    float* p1 = p0 + (size_t)N_P * 64;
    float* g0 = p1 + (size_t)N_P * 64;
    float* g1 = g0 + (size_t)N_G * 64;
    int* ib = (int*)(g1 + (size_t)N_G * 64);
    int* rowptr_g  = ib;  ib += N_G + 1;
    int* rowptr_p  = ib;  ib += N_P + 1;
    int* bucket_cnt    = ib;  ib += NB_MAX;
    int* bucket_base   = ib;  ib += NB_MAX + 1;
    int* bucket_cursor = ib;  ib += NB_MAX;
    int* csr_g = ib;  ib += NE;
    int* csr_p = ib;  ib += NE;
    short* BfragH = (short*)ib;         // 32*64*4*8 = 65536 shorts
    short* BfragL = BfragH + KSTEPS * 64 * 4 * 8;
    // binned (src,dst) pairs alias p1: p1 is first written by bin_fill, strictly
    // after lin_go_reduce (stream-ordered); lin partials live only in g0/g1.
    int2* binned = (int2*)p1;           // NE * 8B = 12.8MB <= N_P*64*4B = 25.6MB

    gather_rows<<<(N_P * (DD / 4) + 255) / 256, 256, 0, stream>>>(protein_emb, protein_nid, p0, N_P);
    pack_B<<<(KSTEPS * 64 * 4 + 255) / 256, 256, 0, stream>>>(lin_W, BfragH, BfragL);
    // 2-way K-split linear with software prefetch: partials into g0/g1, then reduce.
    lin_go_part<<<2 * (N_G / 64), 256, 0, stream>>>(go_x, BfragH, BfragL, g0, g1);
    lin_go_reduce<<<(N_G * 16 + 255) / 256, 256, 0, stream>>>(g0, g1, lin_b, go_emb, go_nid);

    int nblk_fill = (NE + CHUNK - 1) / CHUNK;   // 196

    // ---- CSR for protein->go edges (dst in [0,N_G)) ----
    hipMemsetAsync(bucket_cnt, 0, NB_MAX * sizeof(int), stream);
    bin_count<<<256, 256, 0, stream>>>(dst_pg, bucket_cnt, NE, SHIFT_G, NB_G);
    scan_buckets<<<1, 256, 0, stream>>>(bucket_cnt, bucket_base, bucket_cursor, NB_G, NE);
    bin_fill<<<nblk_fill, 256, 0, stream>>>(src_pg, dst_pg, bucket_cursor, binned, NE, SHIFT_G, NB_G);
    bucket_to_csr<<<NB_G, 256, 0, stream>>>(binned, bucket_base, rowptr_g, csr_g, N_G, SHIFT_G, NE);

    // ---- CSR for go->protein edges (dst in [0,N_P)) ----
    hipMemsetAsync(bucket_cnt, 0, NB_MAX * sizeof(int), stream);
    bin_count<<<256, 256, 0, stream>>>(dst_gp, bucket_cnt, NE, SHIFT_P, NB_P);
    scan_buckets<<<1, 256, 0, stream>>>(bucket_cnt, bucket_base, bucket_cursor, NB_P, NE);
    bin_fill<<<nblk_fill, 256, 0, stream>>>(src_gp, dst_gp, bucket_cursor, binned, NE, SHIFT_P, NB_P);
    bucket_to_csr<<<NB_P, 256, 0, stream>>>(binned, bucket_base, rowptr_p, csr_p, N_P, SHIFT_P, NE);

    float* xp = p0; float* xg = g0; float* sp = p1; float* sg = g1;
    for (int l = 0; l < 3; ++l) {
        aggregate_csr<<<(N_G + 3) / 4, 256, 0, stream>>>(xp, rowptr_g, csr_g, sg, N_G);
        aggregate_csr<<<(N_P + 3) / 4, 256, 0, stream>>>(xg, rowptr_p, csr_p, sp, N_P);
        int relu = (l < 2) ? 1 : 0;
        const float* wl0 = Wl + (size_t)(l * 2 + 0) * 4096;
        const float* wl1 = Wl + (size_t)(l * 2 + 1) * 4096;
        const float* wr0 = Wr + (size_t)(l * 2 + 0) * 4096;
        const float* wr1 = Wr + (size_t)(l * 2 + 1) * 4096;
        const float* b0  = bl + (size_t)(l * 2 + 0) * 64;
        const float* b1  = bl + (size_t)(l * 2 + 1) * 64;
        update_nodes_mfma<<<(N_G + 63) / 64, 256, 0, stream>>>(sg, xg, wl0, b0, wr0, sg, N_G, relu);
        update_nodes_mfma<<<(N_P + 63) / 64, 256, 0, stream>>>(sp, xp, wl1, b1, wr1, sp, N_P, relu);
        float* t;
        t = xp; xp = sp; sp = t;
        t = xg; xg = sg; sg = t;
    }
    classify<<<(E_LBL * 16 + 255) / 256, 256, 0, stream>>>(xp, xg, label_src, label_dst, out, E_LBL);
}

// Round 8
// 939.076 us; speedup vs baseline: 1.0387x; 1.0387x over previous
//
#include <hip/hip_runtime.h>

#define DD 64
constexpr int N_P   = 100000;
constexpr int N_G   = 40000;
constexpr int NE    = 1600000;
constexpr int E_LBL = 500000;
constexpr int F_GO  = 1000;
constexpr int KSTEPS = 32;     // K padded to 1024 = 32 steps of 32

// bucketed counting-sort parameters (big buckets, block-aggregated atomics)
constexpr int SHIFT_G = 8;                         // 256 rows per bucket
constexpr int NB_G    = (N_G + 255) >> 8;          // 157
constexpr int SHIFT_P = 9;                         // 512 rows per bucket
constexpr int NB_P    = (N_P + 511) >> 9;          // 196
constexpr int NB_MAX  = 256;
constexpr int W_MAX   = 512;
constexpr int CHUNK   = 8192;                      // edges per bin_fill block

typedef __attribute__((ext_vector_type(8))) short bf16x8;
typedef __attribute__((ext_vector_type(4))) float f32x4;
typedef __attribute__((ext_vector_type(4))) short s16x4;

// ---- fp32 -> bf16 hi/lo split (RNE) ----
__device__ __forceinline__ unsigned short f2bf_rne(float x) {
    unsigned u = __float_as_uint(x);
    u += 0x7fff + ((u >> 16) & 1);
    return (unsigned short)(u >> 16);
}
__device__ __forceinline__ float bf2f(unsigned short h) {
    return __uint_as_float((unsigned)h << 16);
}
struct BfPair { short h; short l; };
__device__ __forceinline__ BfPair split_bf(float x) {
    BfPair p;
    unsigned short hh = f2bf_rne(x);
    unsigned short ll = f2bf_rne(x - bf2f(hh));
    p.h = (short)hh; p.l = (short)ll;
    return p;
}

// ---------------- gather rows: out[i] = emb[nid[i]] ----------------
__global__ void gather_rows(const float* __restrict__ emb, const int* __restrict__ nid,
                            float* __restrict__ out, int n) {
    int t = blockIdx.x * blockDim.x + threadIdx.x;
    int total = n * (DD / 4);
    if (t >= total) return;
    int row = t / (DD / 4);
    int c4  = t % (DD / 4);
    int srow = nid[row];
    reinterpret_cast<float4*>(out)[(size_t)row * (DD / 4) + c4] =
        reinterpret_cast<const float4*>(emb)[(size_t)srow * (DD / 4) + c4];
}

// ---------------- pack lin_W into MFMA B-fragment order, hi/lo bf16 ----------
__global__ void pack_B(const float* __restrict__ lin_W,
                       short* __restrict__ BH, short* __restrict__ BL) {
    int t = blockIdx.x * blockDim.x + threadIdx.x;
    if (t >= KSTEPS * 64 * 4) return;
    int s = t >> 8, n = (t >> 2) & 63, q = t & 3;
    int base = t * 8;
#pragma unroll
    for (int j = 0; j < 8; ++j) {
        int k = s * 32 + q * 8 + j;
        float v = (k < F_GO) ? lin_W[(size_t)k * 64 + n] : 0.f;
        BfPair p = split_bf(v);
        BH[base + j] = p.h;
        BL[base + j] = p.l;
    }
}

// ---------------- xg = go_x @ lin_W (+ lin_b + go_emb via reduce) ----------------
// K split across BLOCKS 2 ways (R5-proven, verbatim): blockIdx.x&1 -> k-half.
__global__ __launch_bounds__(256) void lin_go_part(const float* __restrict__ go_x,
        const short* __restrict__ BH, const short* __restrict__ BL,
        float* __restrict__ part0, float* __restrict__ part1) {
    int tid = threadIdx.x;
    int wave = tid >> 6, lane = tid & 63;
    int ml = lane & 15, q = lane >> 4;
    int half = blockIdx.x & 1;
    int row0 = (blockIdx.x >> 1) * 64 + wave * 16;   // 625 * 64 = 40000 exactly
    float* outp = half ? part1 : part0;
    const float* arow = go_x + (size_t)(row0 + ml) * F_GO;
    f32x4 acc[4] = {};
    int s0 = half * 16;
    for (int s = s0; s < s0 + 16; ++s) {
        int kb = s * 32 + q * 8;
        int kc = kb > 992 ? 992 : kb;            // clamp tail: B is zero there anyway
        float4 va = *reinterpret_cast<const float4*>(arow + kc);
        float4 vb = *reinterpret_cast<const float4*>(arow + kc + 4);
        bf16x8 ah, al;
        {
            BfPair p0 = split_bf(va.x), p1 = split_bf(va.y),
                   p2 = split_bf(va.z), p3 = split_bf(va.w);
            BfPair p4 = split_bf(vb.x), p5 = split_bf(vb.y),
                   p6 = split_bf(vb.z), p7 = split_bf(vb.w);
            ah[0]=p0.h; ah[1]=p1.h; ah[2]=p2.h; ah[3]=p3.h;
            ah[4]=p4.h; ah[5]=p5.h; ah[6]=p6.h; ah[7]=p7.h;
            al[0]=p0.l; al[1]=p1.l; al[2]=p2.l; al[3]=p3.l;
            al[4]=p4.l; al[5]=p5.l; al[6]=p6.l; al[7]=p7.l;
        }
#pragma unroll
        for (int nt = 0; nt < 4; ++nt) {
            int off = ((s * 64 + nt * 16 + ml) * 4 + q) * 8;
            bf16x8 bh = *reinterpret_cast<const bf16x8*>(BH + off);
            bf16x8 bl = *reinterpret_cast<const bf16x8*>(BL + off);
            acc[nt] = __builtin_amdgcn_mfma_f32_16x16x32_bf16(ah, bh, acc[nt], 0, 0, 0);
            acc[nt] = __builtin_amdgcn_mfma_f32_16x16x32_bf16(al, bh, acc[nt], 0, 0, 0);
            acc[nt] = __builtin_amdgcn_mfma_f32_16x16x32_bf16(ah, bl, acc[nt], 0, 0, 0);
        }
    }
    // epilogue: C/D layout col=lane&15, row=q*4+reg (round-2 mapping, raw partial)
#pragma unroll
    for (int reg = 0; reg < 4; ++reg) {
        int row = row0 + q * 4 + reg;
#pragma unroll
        for (int nt = 0; nt < 4; ++nt) {
            int col = nt * 16 + ml;
            outp[(size_t)row * 64 + col] = acc[nt][reg];
        }
    }
}

// g0 = g0 + g1 + lin_b + go_emb[go_nid]
__global__ void lin_go_reduce(float* __restrict__ g0, const float* __restrict__ g1,
        const float* __restrict__ lin_b, const float* __restrict__ go_emb,
        const int* __restrict__ go_nid) {
    int t = blockIdx.x * blockDim.x + threadIdx.x;
    if (t >= N_G * 16) return;
    int row = t >> 4;
    int c4  = (t & 15) * 4;
    int nid = go_nid[row];
    float4 a  = *reinterpret_cast<const float4*>(g0 + (size_t)row * 64 + c4);
    float4 b  = *reinterpret_cast<const float4*>(g1 + (size_t)row * 64 + c4);
    float4 bb = *reinterpret_cast<const float4*>(lin_b + c4);
    float4 ee = *reinterpret_cast<const float4*>(go_emb + (size_t)nid * 64 + c4);
    float4 r;
    r.x = a.x + b.x + bb.x + ee.x;
    r.y = a.y + b.y + bb.y + ee.y;
    r.z = a.z + b.z + bb.z + ee.z;
    r.w = a.w + b.w + bb.w + ee.w;
    *reinterpret_cast<float4*>(g0 + (size_t)row * 64 + c4) = r;
}

// ================= bucketed CSR build (block-aggregated atomics) =================
// Phase 1: per-block LDS histogram of dst>>shift, one flush atomic per bucket/block
__global__ __launch_bounds__(256) void bin_count(const int* __restrict__ dst,
        int* __restrict__ cnt, int nE, int shift, int nb) {
    __shared__ int h[NB_MAX];
    for (int i = threadIdx.x; i < nb; i += 256) h[i] = 0;
    __syncthreads();
    for (int e = blockIdx.x * blockDim.x + threadIdx.x; e < nE; e += gridDim.x * blockDim.x)
        atomicAdd(&h[dst[e] >> shift], 1);
    __syncthreads();
    for (int i = threadIdx.x; i < nb; i += 256)
        if (h[i]) atomicAdd(&cnt[i], h[i]);
}

// Phase 2: exclusive scan of bucket counts (single block; nb <= 256)
__global__ __launch_bounds__(256) void scan_buckets(const int* __restrict__ cnt,
        int* __restrict__ base, int* __restrict__ cursor, int nb, int total) {
    __shared__ int sh[NB_MAX];
    int v = (threadIdx.x < nb) ? cnt[threadIdx.x] : 0;
    sh[threadIdx.x] = v;
    __syncthreads();
    for (int off = 1; off < NB_MAX; off <<= 1) {
        int t = (threadIdx.x >= off) ? sh[threadIdx.x - off] : 0;
        __syncthreads();
        sh[threadIdx.x] += t;
        __syncthreads();
    }
    if (threadIdx.x < nb) {
        int ex = sh[threadIdx.x] - v;
        base[threadIdx.x] = ex;
        cursor[threadIdx.x] = ex;
    }
    if (threadIdx.x == 0) base[nb] = total;
}

// Phase 3: per-block LDS histogram -> ONE global atomic reservation per bucket,
// then scatter pairs into the block's private contiguous segments.
__global__ __launch_bounds__(256) void bin_fill(const int* __restrict__ src,
        const int* __restrict__ dst, int* __restrict__ cursor,
        int2* __restrict__ binned, int nE, int shift, int nb) {
    __shared__ int hist[NB_MAX];
    __shared__ int base[NB_MAX];
    int e0 = blockIdx.x * CHUNK;
    int e1 = e0 + CHUNK; if (e1 > nE) e1 = nE;
    for (int i = threadIdx.x; i < nb; i += 256) hist[i] = 0;
    __syncthreads();
    for (int e = e0 + threadIdx.x; e < e1; e += 256)
        atomicAdd(&hist[dst[e] >> shift], 1);
    __syncthreads();
    // one reservation atomic per (block, bucket); same thread owns index i in both loops
    for (int i = threadIdx.x; i < nb; i += 256) {
        int c = hist[i];
        base[i] = c ? atomicAdd(&cursor[i], c) : 0;
        hist[i] = 0;                       // becomes the block-local running cursor
    }
    __syncthreads();
    for (int e = e0 + threadIdx.x; e < e1; e += 256) {
        int d = dst[e];
        int b = d >> shift;
        int slot = base[b] + atomicAdd(&hist[b], 1);
        binned[slot] = make_int2(src[e], d);
    }
}

// Phase 4: one workgroup per bucket. LDS histogram over the bucket's dst range,
// parallel scan -> rowptr, then scatter csr_src into the bucket's contiguous
// (L2-resident) output window.
__global__ __launch_bounds__(256) void bucket_to_csr(const int2* __restrict__ binned,
        const int* __restrict__ bbase, int* __restrict__ rowptr, int* __restrict__ csr_src,
        int n, int shift, int nE) {
    int b = blockIdx.x;
    int W = 1 << shift;                    // 256 or 512
    int mask = W - 1;
    __shared__ int hist[W_MAX];
    __shared__ int curs[W_MAX];
    int s = bbase[b], e = bbase[b + 1];
    for (int i = threadIdx.x; i < W; i += 256) hist[i] = 0;
    __syncthreads();
    for (int i = s + threadIdx.x; i < e; i += 256)
        atomicAdd(&hist[binned[i].y & mask], 1);
    __syncthreads();
    // inclusive Hillis-Steele scan of hist into curs (W <= 512, 256 threads)
    for (int i = threadIdx.x; i < W; i += 256) curs[i] = hist[i];
    __syncthreads();
    for (int off = 1; off < W; off <<= 1) {
        int i0 = threadIdx.x, i1 = threadIdx.x + 256;
        int t0 = (i0 >= off && i0 < W) ? curs[i0 - off] : 0;
        int t1 = (i1 >= off && i1 < W) ? curs[i1 - off] : 0;
        __syncthreads();
        if (i0 < W) curs[i0] += t0;
        if (i1 < W) curs[i1] += t1;
        __syncthreads();
    }
    int row0 = b << shift;
    for (int j = threadIdx.x; j < W; j += 256) {
        int start = s + curs[j] - hist[j]; // exclusive prefix + bucket base
        hist[j] = start;                   // becomes the per-row running cursor
        int r = row0 + j;
        if (r < n) rowptr[r] = start;
    }
    if (b == 0 && threadIdx.x == 0) rowptr[n] = nE;
    __syncthreads();
    for (int i = s + threadIdx.x; i < e; i += 256) {
        int2 ed = binned[i];
        int slot = atomicAdd(&hist[ed.y & mask], 1);
        csr_src[slot] = ed.x;
    }
}

// ---------------- aggregation (both directions fused) ----------------
// One 16-lane group per row; group owns the whole row (no cross-lane reduce);
// 8 gathers in flight per lane for Little's-law BW. Blocks never straddle the
// GO/protein boundary (16 | N_G).
__global__ __launch_bounds__(256) void aggregate_both(
        const float* __restrict__ xp, const float* __restrict__ xg,
        const int* __restrict__ rowptr_g, const int* __restrict__ csr_g,
        const int* __restrict__ rowptr_p, const int* __restrict__ csr_p,
        float* __restrict__ sg, float* __restrict__ sp) {
    int grp = (blockIdx.x << 4) + (threadIdx.x >> 4);   // global row id over G then P
    int l16 = threadIdx.x & 15;
    const float4* x4; const int* rp; const int* cs; float* o; int row;
    if (grp < N_G) {
        x4 = reinterpret_cast<const float4*>(xp);
        rp = rowptr_g; cs = csr_g; o = sg; row = grp;
    } else {
        x4 = reinterpret_cast<const float4*>(xg);
        rp = rowptr_p; cs = csr_p; o = sp; row = grp - N_G;
    }
    int s = rp[row], e = rp[row + 1];
    float4 a0 = make_float4(0.f, 0.f, 0.f, 0.f);
    float4 a1 = make_float4(0.f, 0.f, 0.f, 0.f);
    float4 a2 = make_float4(0.f, 0.f, 0.f, 0.f);
    float4 a3 = make_float4(0.f, 0.f, 0.f, 0.f);
    int i = s;
    for (; i + 8 <= e; i += 8) {
        int s0 = cs[i],     s1 = cs[i + 1], s2 = cs[i + 2], s3 = cs[i + 3];
        int s4 = cs[i + 4], s5 = cs[i + 5], s6 = cs[i + 6], s7 = cs[i + 7];
        float4 v0 = x4[(size_t)s0 * 16 + l16];
        float4 v1 = x4[(size_t)s1 * 16 + l16];
        float4 v2 = x4[(size_t)s2 * 16 + l16];
        float4 v3 = x4[(size_t)s3 * 16 + l16];
        float4 v4 = x4[(size_t)s4 * 16 + l16];
        float4 v5 = x4[(size_t)s5 * 16 + l16];
        float4 v6 = x4[(size_t)s6 * 16 + l16];
        float4 v7 = x4[(size_t)s7 * 16 + l16];
        a0.x += v0.x; a0.y += v0.y; a0.z += v0.z; a0.w += v0.w;
        a1.x += v1.x; a1.y += v1.y; a1.z += v1.z; a1.w += v1.w;
        a2.x += v2.x; a2.y += v2.y; a2.z += v2.z; a2.w += v2.w;
        a3.x += v3.x; a3.y += v3.y; a3.z += v3.z; a3.w += v3.w;
        a0.x += v4.x; a0.y += v4.y; a0.z += v4.z; a0.w += v4.w;
        a1.x += v5.x; a1.y += v5.y; a1.z += v5.z; a1.w += v5.w;
        a2.x += v6.x; a2.y += v6.y; a2.z += v6.z; a2.w += v6.w;
        a3.x += v7.x; a3.y += v7.y; a3.z += v7.z; a3.w += v7.w;
    }
    for (; i < e; ++i) {
        int s0 = cs[i];
        float4 v0 = x4[(size_t)s0 * 16 + l16];
        a0.x += v0.x; a0.y += v0.y; a0.z += v0.z; a0.w += v0.w;
    }
    a0.x += a1.x; a0.y += a1.y; a0.z += a1.z; a0.w += a1.w;
    a2.x += a3.x; a2.y += a3.y; a2.z += a3.z; a2.w += a3.w;
    a0.x += a2.x; a0.y += a2.y; a0.z += a2.z; a0.w += a2.w;
    float inv = (e > s) ? 1.0f / (float)(e - s) : 0.0f;
    float4 r = make_float4(a0.x * inv, a0.y * inv, a0.z * inv, a0.w * inv);
    reinterpret_cast<float4*>(o)[(size_t)row * 16 + l16] = r;
}

// ---------------- node update: out = agg@Wl + bias + x@Wr (bf16x3 MFMA) ----
constexpr int LDA_UN = 72;
__global__ __launch_bounds__(256) void update_nodes_mfma(
        const float* agg, const float* __restrict__ x,
        const float* __restrict__ Wl, const float* __restrict__ bias,
        const float* __restrict__ Wr, float* out, int n, int relu) {
    __shared__ short Ah[64][LDA_UN], Al[64][LDA_UN];
    __shared__ short Bh[64][LDA_UN], Bl[64][LDA_UN];
    int tid = threadIdx.x;
    int wave = tid >> 6, lane = tid & 63;
    int ml = lane & 15, q = lane >> 4;
    int row0 = blockIdx.x * 64;
    f32x4 acc[4] = {};
    for (int half = 0; half < 2; ++half) {
        const float* Xsrc = half ? x : agg;
        const float* Wsrc = half ? Wr : Wl;
        {
            int k4 = tid & 15;
            for (int r = tid >> 4; r < 64; r += 16) {
                int grow = row0 + r; if (grow >= n) grow = n - 1;
                float4 v = *reinterpret_cast<const float4*>(&Xsrc[(size_t)grow * 64 + k4 * 4]);
                s16x4 h, l;
                BfPair p0 = split_bf(v.x), p1 = split_bf(v.y),
                       p2 = split_bf(v.z), p3 = split_bf(v.w);
                h[0] = p0.h; h[1] = p1.h; h[2] = p2.h; h[3] = p3.h;
                l[0] = p0.l; l[1] = p1.l; l[2] = p2.l; l[3] = p3.l;
                *reinterpret_cast<s16x4*>(&Ah[r][k4 * 4]) = h;
                *reinterpret_cast<s16x4*>(&Al[r][k4 * 4]) = l;
            }
        }
        {
            int nn = tid & 63;
            for (int kr = tid >> 6; kr < 64; kr += 4) {
                float v = Wsrc[(size_t)kr * 64 + nn];
                BfPair p = split_bf(v);
                Bh[nn][kr] = p.h; Bl[nn][kr] = p.l;
            }
        }
        __syncthreads();
#pragma unroll
        for (int kc = 0; kc < 64; kc += 32) {
            int kb = kc + q * 8;
            int m = wave * 16 + ml;
            bf16x8 ah = *reinterpret_cast<const bf16x8*>(&Ah[m][kb]);
            bf16x8 al = *reinterpret_cast<const bf16x8*>(&Al[m][kb]);
#pragma unroll
            for (int nt = 0; nt < 4; ++nt) {
                int nn = nt * 16 + ml;
                bf16x8 bh = *reinterpret_cast<const bf16x8*>(&Bh[nn][kb]);
                bf16x8 bl = *reinterpret_cast<const bf16x8*>(&Bl[nn][kb]);
                acc[nt] = __builtin_amdgcn_mfma_f32_16x16x32_bf16(ah, bh, acc[nt], 0, 0, 0);
                acc[nt] = __builtin_amdgcn_mfma_f32_16x16x32_bf16(al, bh, acc[nt], 0, 0, 0);
                acc[nt] = __builtin_amdgcn_mfma_f32_16x16x32_bf16(ah, bl, acc[nt], 0, 0, 0);
            }
        }
        __syncthreads();
    }
#pragma unroll
    for (int reg = 0; reg < 4; ++reg) {
        int row = row0 + wave * 16 + q * 4 + reg;
        if (row >= n) continue;
#pragma unroll
        for (int nt = 0; nt < 4; ++nt) {
            int col = nt * 16 + ml;
            float v = acc[nt][reg] + bias[col];
            if (relu) v = fmaxf(v, 0.0f);
            out[(size_t)row * 64 + col] = v;
        }
    }
}

// ---------------- classifier ----------------
__global__ void classify(const float* __restrict__ xp, const float* __restrict__ xg,
                         const int* __restrict__ ls, const int* __restrict__ ld,
                         float* __restrict__ out, int nE) {
    int t = blockIdx.x * blockDim.x + threadIdx.x;
    int e = t >> 4;
    int l16 = t & 15;
    if (e >= nE) return;
    int s = ls[e], d = ld[e];
    float4 a = reinterpret_cast<const float4*>(xp)[(size_t)s * 16 + l16];
    float4 b = reinterpret_cast<const float4*>(xg)[(size_t)d * 16 + l16];
    float v = a.x * b.x + a.y * b.y + a.z * b.z + a.w * b.w;
    v += __shfl_xor(v, 8);
    v += __shfl_xor(v, 4);
    v += __shfl_xor(v, 2);
    v += __shfl_xor(v, 1);
    if (l16 == 0) out[e] = v;
}

extern "C" void kernel_launch(void* const* d_in, const int* in_sizes, int n_in,
                              void* d_out, int out_size, void* d_ws, size_t ws_size,
                              hipStream_t stream) {
    const float* go_x        = (const float*)d_in[0];
    const float* protein_emb = (const float*)d_in[1];
    const float* go_emb      = (const float*)d_in[2];
    const float* lin_W       = (const float*)d_in[3];
    const float* lin_b       = (const float*)d_in[4];
    const float* Wl          = (const float*)d_in[5];
    const float* bl          = (const float*)d_in[6];
    const float* Wr          = (const float*)d_in[7];
    const int* protein_nid   = (const int*)d_in[8];
    const int* go_nid        = (const int*)d_in[9];
    const int* src_pg        = (const int*)d_in[10];
    const int* dst_pg        = (const int*)d_in[11];
    const int* src_gp        = (const int*)d_in[12];
    const int* dst_gp        = (const int*)d_in[13];
    const int* label_src     = (const int*)d_in[14];
    const int* label_dst     = (const int*)d_in[15];
    float* out = (float*)d_out;

    float* ws = (float*)d_ws;
    float* p0 = ws;
    float* p1 = p0 + (size_t)N_P * 64;
    float* g0 = p1 + (size_t)N_P * 64;
    float* g1 = g0 + (size_t)N_G * 64;
    int* ib = (int*)(g1 + (size_t)N_G * 64);
    int* rowptr_g  = ib;  ib += N_G + 1;
    int* rowptr_p  = ib;  ib += N_P + 1;
    int* bucket_cnt    = ib;  ib += NB_MAX;
    int* bucket_base   = ib;  ib += NB_MAX + 1;
    int* bucket_cursor = ib;  ib += NB_MAX;
    int* csr_g = ib;  ib += NE;
    int* csr_p = ib;  ib += NE;
    short* BfragH = (short*)ib;         // 32*64*4*8 = 65536 shorts
    short* BfragL = BfragH + KSTEPS * 64 * 4 * 8;
    // binned (src,dst) pairs alias p1: p1 is first written by bin_fill, strictly
    // after lin_go_reduce (stream-ordered); lin partials live only in g0/g1.
    int2* binned = (int2*)p1;           // NE * 8B = 12.8MB <= N_P*64*4B = 25.6MB

    gather_rows<<<(N_P * (DD / 4) + 255) / 256, 256, 0, stream>>>(protein_emb, protein_nid, p0, N_P);
    pack_B<<<(KSTEPS * 64 * 4 + 255) / 256, 256, 0, stream>>>(lin_W, BfragH, BfragL);
    // 2-way K-split linear (R5-proven): partials into g0/g1, then reduce.
    lin_go_part<<<2 * (N_G / 64), 256, 0, stream>>>(go_x, BfragH, BfragL, g0, g1);
    lin_go_reduce<<<(N_G * 16 + 255) / 256, 256, 0, stream>>>(g0, g1, lin_b, go_emb, go_nid);

    int nblk_fill = (NE + CHUNK - 1) / CHUNK;   // 196

    // ---- CSR for protein->go edges (dst in [0,N_G)) ----
    hipMemsetAsync(bucket_cnt, 0, NB_MAX * sizeof(int), stream);
    bin_count<<<256, 256, 0, stream>>>(dst_pg, bucket_cnt, NE, SHIFT_G, NB_G);
    scan_buckets<<<1, 256, 0, stream>>>(bucket_cnt, bucket_base, bucket_cursor, NB_G, NE);
    bin_fill<<<nblk_fill, 256, 0, stream>>>(src_pg, dst_pg, bucket_cursor, binned, NE, SHIFT_G, NB_G);
    bucket_to_csr<<<NB_G, 256, 0, stream>>>(binned, bucket_base, rowptr_g, csr_g, N_G, SHIFT_G, NE);

    // ---- CSR for go->protein edges (dst in [0,N_P)) ----
    hipMemsetAsync(bucket_cnt, 0, NB_MAX * sizeof(int), stream);
    bin_count<<<256, 256, 0, stream>>>(dst_gp, bucket_cnt, NE, SHIFT_P, NB_P);
    scan_buckets<<<1, 256, 0, stream>>>(bucket_cnt, bucket_base, bucket_cursor, NB_P, NE);
    bin_fill<<<nblk_fill, 256, 0, stream>>>(src_gp, dst_gp, bucket_cursor, binned, NE, SHIFT_P, NB_P);
    bucket_to_csr<<<NB_P, 256, 0, stream>>>(binned, bucket_base, rowptr_p, csr_p, N_P, SHIFT_P, NE);

    float* xp = p0; float* xg = g0; float* sp = p1; float* sg = g1;
    for (int l = 0; l < 3; ++l) {
        aggregate_both<<<(N_G + N_P) / 16, 256, 0, stream>>>(
            xp, xg, rowptr_g, csr_g, rowptr_p, csr_p, sg, sp);
        int relu = (l < 2) ? 1 : 0;
        const float* wl0 = Wl + (size_t)(l * 2 + 0) * 4096;
        const float* wl1 = Wl + (size_t)(l * 2 + 1) * 4096;
        const float* wr0 = Wr + (size_t)(l * 2 + 0) * 4096;
        const float* wr1 = Wr + (size_t)(l * 2 + 1) * 4096;
        const float* b0  = bl + (size_t)(l * 2 + 0) * 64;
        const float* b1  = bl + (size_t)(l * 2 + 1) * 64;
        update_nodes_mfma<<<(N_G + 63) / 64, 256, 0, stream>>>(sg, xg, wl0, b0, wr0, sg, N_G, relu);
        update_nodes_mfma<<<(N_P + 63) / 64, 256, 0, stream>>>(sp, xp, wl1, b1, wr1, sp, N_P, relu);
        float* t;
        t = xp; xp = sp; sp = t;
        t = xg; xg = sg; sg = t;
    }
    classify<<<(E_LBL * 16 + 255) / 256, 256, 0, stream>>>(xp, xg, label_src, label_dst, out, E_LBL);
}